// Round 8
// baseline (93.968 us; speedup 1.0000x reference)
//
#include <hip/hip_runtime.h>

// SSIM map — round-8: persistent 32-col strip, 74-slot ring LDS, prefetch.
// B=16, C=3, H=W=512, 11-tap separable gaussian (sigma=1.5).
//
// One block = one 32x512 column strip (grid 16x1x48 = 768 blocks = exactly
// 3 resident/CU, no tail). Strip processed in 8 chunks of 64 output rows
// through a 74-slot ring buffer (union raw/hf layout, pitch 164 floats,
// identical to round-7):  slot(row) = (row+5) mod 74.
//   raw: words 0..95 (48 cols x interleaved (x,y));  hf: words 0..127
//   (float4 x,y,xx,yy per col) + 128..159 (xy).
//
// Per chunk k (steady state), 3 barriers:
//   [prefetch k+1]: issue 64 rows x 12 float4-pairs of global loads into
//       REGISTERS (1.5 items/thread) — in flight during all of S3 (T14).
//   S3: v-conv + SSIM for out rows 64k..64k+63; ring reads via cndmask'd
//       wrapped/unwrapped base pointers (d*PITCH folds into ds offset).
//   bar; W: ds_write prefetched raw — lands exactly in the slots whose hf
//       rows (64k-5..64k+58) S3 just finished reading.
//   bar; S2: h-conv ONLY the 64 new rows (256 8-col items, waves 0-3;
//       same wave-local row ownership -> in-place raw->hf aliasing safe).
//   bar.
// Prologue: stage rows -5..68 into slots 0..73 + h-conv them (round-7 code).
//
// vs round-7 (65.75us): stage-1/2 rows 592->522 per strip (-12% work and
// -12% fetch: y-halo re-staging eliminated), HBM latency hidden under
// v-conv instead of serialized at block start, no dispatch tail.
// Accumulation order identical to round-7 (bitwise-same output).

#define Wd    512
#define Hd    512
#define BC    48
#define TX    32
#define RS    74          // ring slots (64 chunk + 10 halo)
#define IC4   12          // float4 cols staged per row (48 cols: c0-8..c0+39)
#define PITCH 164         // floats/row: 656B = 41 float4s (odd: bank stagger)
#define NT    512

__device__ __forceinline__ float2 pk_mul2(float2 a, float2 b) {
    float2 d;
    asm("v_pk_mul_f32 %0, %1, %2" : "=v"(d) : "v"(a), "v"(b));
    return d;
}
// acc = w*v + acc (both lanes); w uniform -> SGPR pair
__device__ __forceinline__ void pk_fma2(float2& acc, float2 w, float2 v) {
    asm("v_pk_fma_f32 %0, %1, %2, %0" : "+v"(acc) : "s"(w), "v"(v));
}

// 8-col horizontal conv of one raw row (in-place union write), round-7 body.
__device__ __forceinline__ void hconv8(float (*buf)[PITCH], const float* g,
                                       int row, int cb) {
    const float* __restrict__ rb = &buf[row][2 * cb + 4];
    float2 A01[8], A23[8];
    float  A4[8];
#pragma unroll
    for (int j = 0; j < 8; ++j) {
        A01[j] = make_float2(0.f, 0.f);
        A23[j] = make_float2(0.f, 0.f);
        A4[j]  = 0.f;
    }
    float4 q4[10];
#pragma unroll
    for (int q = 0; q < 5; ++q)                  // batch A
        q4[q] = *reinterpret_cast<const float4*>(rb + 4 * q);
#pragma unroll
    for (int kk = 0; kk < 8; ++kk) {
        const float4 f = q4[(kk + 1) >> 1];
        const float2 vv = (kk & 1) ? make_float2(f.x, f.y)
                                   : make_float2(f.z, f.w);
        const float2 pp  = pk_mul2(vv, vv);
        const float  pxy = vv.x * vv.y;
#pragma unroll
        for (int j = 0; j < 8; ++j) {
            const int m = kk - j;
            if (m >= 0 && m <= 10) {
                const float2 w2 = make_float2(g[m], g[m]);
                pk_fma2(A01[j], w2, vv);
                pk_fma2(A23[j], w2, pp);
                A4[j] = fmaf(g[m], pxy, A4[j]);
            }
        }
    }
#pragma unroll
    for (int q = 5; q < 10; ++q)                 // batch B
        q4[q] = *reinterpret_cast<const float4*>(rb + 4 * q);
#pragma unroll
    for (int kk = 8; kk < 18; ++kk) {
        const float4 f = q4[(kk + 1) >> 1];
        const float2 vv = (kk & 1) ? make_float2(f.x, f.y)
                                   : make_float2(f.z, f.w);
        const float2 pp  = pk_mul2(vv, vv);
        const float  pxy = vv.x * vv.y;
#pragma unroll
        for (int j = 0; j < 8; ++j) {
            const int m = kk - j;
            if (m >= 0 && m <= 10) {
                const float2 w2 = make_float2(g[m], g[m]);
                pk_fma2(A01[j], w2, vv);
                pk_fma2(A23[j], w2, pp);
                A4[j] = fmaf(g[m], pxy, A4[j]);
            }
        }
    }
#pragma unroll
    for (int j = 0; j < 8; ++j) {
        *reinterpret_cast<float4*>(&buf[row][4 * (cb + j)]) =
            make_float4(A01[j].x, A01[j].y, A23[j].x, A23[j].y);
    }
    *reinterpret_cast<float4*>(&buf[row][128 + cb]) =
        make_float4(A4[0], A4[1], A4[2], A4[3]);
    *reinterpret_cast<float4*>(&buf[row][128 + cb + 4]) =
        make_float4(A4[4], A4[5], A4[6], A4[7]);
}

__global__ __launch_bounds__(NT, 6) void ssim_kernel(
    const float* __restrict__ x, const float* __restrict__ y,
    float* __restrict__ out)
{
    __shared__ __align__(16) float buf[RS][PITCH];   // 48544 B -> 3 blocks/CU

    // fp32-normalized gaussian, sigma=1.5, K=11 (matches np reference ~1e-7)
    const float g[11] = {
        0.00102838f, 0.00759875f, 0.03600077f, 0.10936069f, 0.21300553f,
        0.26601172f,
        0.21300553f, 0.10936069f, 0.03600077f, 0.00759875f, 0.00102838f};

    const int tid = threadIdx.x;
    const int bc  = blockIdx.z;
    const int c0  = blockIdx.x * TX;

    const float* __restrict__ xp = x + (size_t)bc * Hd * Wd;
    const float* __restrict__ yp = y + (size_t)bc * Hd * Wd;
    float* __restrict__ op = out + (size_t)bc * Hd * Wd;

    const bool xin = (blockIdx.x > 0) && (blockIdx.x < (Wd / TX) - 1);

    // ---- Prologue stage 1: rows -5..68 -> slots 0..73 ----
#pragma unroll
    for (int it = 0; it < 2; ++it) {
        const int idx = tid + it * NT;
        if (idx < RS * IC4) {
            const int r  = idx / IC4;
            const int c4 = idx - r * IC4;
            const int gr = r - 5;
            const int gc = c0 - 8 + 4 * c4;
            const bool ok = (gr >= 0) && (xin || (unsigned)gc < (unsigned)Wd);
            float4 lx = make_float4(0.f, 0.f, 0.f, 0.f), ly = lx;
            if (ok) {
                const size_t gi = ((size_t)gr << 9) + gc;
                lx = *reinterpret_cast<const float4*>(xp + gi);
                ly = *reinterpret_cast<const float4*>(yp + gi);
            }
            *reinterpret_cast<float4*>(&buf[r][8 * c4]) =
                make_float4(lx.x, ly.x, lx.y, ly.y);
            *reinterpret_cast<float4*>(&buf[r][8 * c4 + 4]) =
                make_float4(lx.z, ly.z, lx.w, ly.w);
        }
    }
    __syncthreads();

    // ---- Prologue stage 2: h-conv slots 0..73 (296 items, 5-wave map) ----
    {
        const int l = tid & 63, wid = tid >> 6;
        int row, cg;
        if (wid < 4) { row = (wid << 4) + ((l >> 5) << 3) + (l & 7); cg = (l >> 3) & 3; }
        else         { row = 64 + (l >> 2);                          cg = l & 3; }
        if ((wid < 4) || (wid == 4 && l < 40))
            hconv8(buf, g, row, cg << 3);
    }
    __syncthreads();

    // ---- hoisted invariants ----
    const int tx = tid & 31;
    const int og = (tid >> 5) << 2;              // output row group 0,4,..,60
    // prefetch items: 768 = 64 rows x 12 f4-cols; item0 = tid, item1 = tid+512
    const int i_row0 = tid / IC4, c40 = tid - i_row0 * IC4;
    const int i_row1 = (tid + NT) / IC4, c41 = (tid + NT) - i_row1 * IC4;
    const int  gc0 = c0 - 8 + 4 * c40;
    const int  gc1 = c0 - 8 + 4 * c41;
    const bool okc0 = xin || (unsigned)gc0 < (unsigned)Wd;
    const bool okc1 = xin || (unsigned)gc1 < (unsigned)Wd;
    // steady S2 (waves 0-3): row 0..63, colgroup
    const int l6 = tid & 63;
    const int s2row = ((tid >> 6) & 3) * 16 + ((l6 >> 5) << 3) + (l6 & 7);
    const int s2cb  = (((l6 >> 3) & 3)) << 3;

    int base74 = 0;                  // (64k) mod 74
    int grow0  = 69 + i_row0;        // global row of prefetch item0
    int grow1  = 69 + i_row1;
    int orow   = og;                 // output row base (64k + og)

#pragma unroll 1
    for (int k = 0; k < 8; ++k) {
        // ---- prefetch issue for chunk k+1 (in flight across S3) ----
        float4 plx0, ply0, plx1, ply1;
        int pw0 = 0, pw1 = 0;
        if (k < 7) {
            {
                int slot = base74 + i_row0; if (slot >= RS) slot -= RS;
                pw0 = slot * PITCH + 8 * c40;
                plx0 = make_float4(0.f, 0.f, 0.f, 0.f); ply0 = plx0;
                if (okc0 && (grow0 < Hd)) {
                    const size_t gi = ((size_t)grow0 << 9) + gc0;
                    plx0 = *reinterpret_cast<const float4*>(xp + gi);
                    ply0 = *reinterpret_cast<const float4*>(yp + gi);
                }
            }
            if (tid < 256) {
                int slot = base74 + i_row1; if (slot >= RS) slot -= RS;
                pw1 = slot * PITCH + 8 * c41;
                plx1 = make_float4(0.f, 0.f, 0.f, 0.f); ply1 = plx1;
                if (okc1 && (grow1 < Hd)) {
                    const size_t gi = ((size_t)grow1 << 9) + gc1;
                    plx1 = *reinterpret_cast<const float4*>(xp + gi);
                    ply1 = *reinterpret_cast<const float4*>(yp + gi);
                }
            }
        }

        // ---- S3: v-conv + SSIM, out rows orow..orow+3 ----
        {
            int bb = base74 + og; if (bb >= RS) bb -= RS;
            const float* p4 = &buf[0][0] + bb * PITCH + 4 * tx;
            const float* px_ = &buf[0][0] + bb * PITCH + 128 + tx;

            float2 acc01[4], acc23[4];
            float  acc4[4];
#pragma unroll
            for (int j = 0; j < 4; ++j) {
                acc01[j] = make_float2(0.f, 0.f);
                acc23[j] = make_float2(0.f, 0.f);
                acc4[j]  = 0.f;
            }
#pragma unroll
            for (int d = 0; d < 14; ++d) {
                const int   sub = ((bb + d) >= RS) ? RS * PITCH : 0;  // ring wrap
                const float4 h4 =
                    *reinterpret_cast<const float4*>(p4 + d * PITCH - sub);
                const float  h5 = *(px_ + d * PITCH - sub);
                const float2 h01 = make_float2(h4.x, h4.y);
                const float2 h23 = make_float2(h4.z, h4.w);
#pragma unroll
                for (int j = 0; j < 4; ++j) {
                    const int m = d - j;
                    if (m >= 0 && m <= 10) {
                        const float2 w2 = make_float2(g[m], g[m]);
                        pk_fma2(acc01[j], w2, h01);
                        pk_fma2(acc23[j], w2, h23);
                        acc4[j] = fmaf(g[m], h5, acc4[j]);
                    }
                }
            }
#pragma unroll
            for (int j = 0; j < 4; ++j) {
                const float2 a01  = acc01[j];
                const float2 musq = pk_mul2(a01, a01);   // (mu1^2, mu2^2)
                const float  mu12 = a01.x * a01.y;
                const float  s1   = acc23[j].x - musq.x;
                const float  s2   = acc23[j].y - musq.y;
                const float  s12  = acc4[j]    - mu12;
                const float num = fmaf(2.f, mu12, 1e-4f) * fmaf(2.f, s12, 9e-4f);
                const float den = ((musq.x + musq.y) + 1e-4f) * ((s1 + s2) + 9e-4f);
                op[(size_t)(orow + j) * Wd + c0 + tx] =
                    num * __builtin_amdgcn_rcpf(den);
            }
        }
        __syncthreads();

        if (k < 7) {
            // ---- W: write prefetched raw rows (slots just freed by S3) ----
            {
                float* wp = &buf[0][0] + pw0;
                *reinterpret_cast<float4*>(wp) =
                    make_float4(plx0.x, ply0.x, plx0.y, ply0.y);
                *reinterpret_cast<float4*>(wp + 4) =
                    make_float4(plx0.z, ply0.z, plx0.w, ply0.w);
            }
            if (tid < 256) {
                float* wp = &buf[0][0] + pw1;
                *reinterpret_cast<float4*>(wp) =
                    make_float4(plx1.x, ply1.x, plx1.y, ply1.y);
                *reinterpret_cast<float4*>(wp + 4) =
                    make_float4(plx1.z, ply1.z, plx1.w, ply1.w);
            }
            __syncthreads();

            // ---- S2: h-conv the 64 new rows (waves 0-3) ----
            if (tid < 256) {
                int slot = base74 + s2row; if (slot >= RS) slot -= RS;
                hconv8(buf, g, slot, s2cb);
            }
            __syncthreads();

            base74 += 64; if (base74 >= RS) base74 -= RS;
            grow0 += 64; grow1 += 64;
        }
        orow += 64;
    }
}

extern "C" void kernel_launch(void* const* d_in, const int* in_sizes, int n_in,
                              void* d_out, int out_size, void* d_ws, size_t ws_size,
                              hipStream_t stream) {
    const float* img_out    = (const float*)d_in[0];
    const float* img_target = (const float*)d_in[1];
    // d_in[2] is window_size==11; fixed by the problem, baked into the kernel.
    float* out = (float*)d_out;

    dim3 grid(Wd / TX, 1, BC);   // 16 x 1 x 48 = 768 blocks = 3/CU exactly
    ssim_kernel<<<grid, NT, 0, stream>>>(img_out, img_target, out);
}

// Round 9
// 58.035 us; speedup vs baseline: 1.6192x; 1.6192x over previous
//
#include <hip/hip_runtime.h>

// SSIM map — round-9: round-7 tile kernel + XCD-channel block swizzle.
// B=16, C=3, H=W=512, 11-tap separable gaussian (sigma=1.5).
//
// Kernel body identical to round-7 (best: 65.75us): 32x64 tile, 512 thr,
// union LDS [74][164]f (48.5KB -> 3 blk/CU), 2 barriers, pk_fma math,
// 8-col stage-2 items, float4 stage-1, wave-local raw->hf aliasing.
//
// NEW: XCD-aware tile remap. Linear dispatch round-robins consecutive
// blocks over 8 XCDs, so x-adjacent tiles (shared 16-col halo + shared
// 128B cache lines at staging-window edges) land on different per-XCD L2s
// -> halo re-reads hit HBM (FETCH 141MB vs 100.6MB compulsory = 1.40x).
// Remap tile = (lin%8)*768 + lin/8  (bijective: 6144 = 8*768): each XCD
// owns 6 whole channels; one channel's x+y = 2MB fits its 4MB L2, so both
// x- and y-halo re-reads become L2 hits.
//
// Round-8 post-mortem (94us): register prefetch across S3 spilled to
// scratch (+93MB WRITE / +78MB FETCH = spill traffic), VALUBusy 35%.
// Reverted; this round cuts the HBM phase (31us of ~67) instead.

#define W     512
#define H     512
#define BC    48
#define TX    32
#define TY    64
#define IY    74          // TY + 10
#define IC4   12          // float4 cols staged per row (48 cols: c0-8..c0+39)
#define PITCH 164         // floats/row: 656B = 41 float4s (odd: bank stagger)
#define NT    512

__device__ __forceinline__ float2 pk_mul2(float2 a, float2 b) {
    float2 d;
    asm("v_pk_mul_f32 %0, %1, %2" : "=v"(d) : "v"(a), "v"(b));
    return d;
}
// acc = w*v + acc  (both lanes); w uniform -> SGPR pair
__device__ __forceinline__ void pk_fma2(float2& acc, float2 w, float2 v) {
    asm("v_pk_fma_f32 %0, %1, %2, %0" : "+v"(acc) : "s"(w), "v"(v));
}

__global__ __launch_bounds__(NT, 6) void ssim_kernel(
    const float* __restrict__ x, const float* __restrict__ y,
    float* __restrict__ out)
{
    __shared__ __align__(16) float buf[IY][PITCH];   // 48544 B -> 3 blocks/CU

    // fp32-normalized gaussian, sigma=1.5, K=11 (matches np reference ~1e-7)
    const float g[11] = {
        0.00102838f, 0.00759875f, 0.03600077f, 0.10936069f, 0.21300553f,
        0.26601172f,
        0.21300553f, 0.10936069f, 0.03600077f, 0.00759875f, 0.00102838f};

    const int tid = threadIdx.x;

    // ---- XCD-channel swizzle: lin -> (xcd owns 768 consecutive tiles) ----
    const int lin  = blockIdx.x + (blockIdx.y << 4) + (blockIdx.z << 7);
    const int tile = ((lin & 7) * 768) + (lin >> 3);   // bijective, 6144=8*768
    const int bc   = tile >> 7;                        // channel 0..47
    const int tyi  = (tile >> 4) & 7;                  // tile row 0..7
    const int txi  = tile & 15;                        // tile col 0..15
    const int c0   = txi * TX;
    const int r0   = tyi * TY;

    const float* __restrict__ xp = x + (size_t)bc * H * W;
    const float* __restrict__ yp = y + (size_t)bc * H * W;

    const bool xin = (txi > 0) && (txi < (W / TX) - 1);

    // ---- Stage 1: global float4 -> LDS interleaved (x,y) pairs ----
    // item = r*12 + c4; cols gc = c0-8+4*c4 (aligned, never straddles edge)
#pragma unroll
    for (int it = 0; it < 2; ++it) {
        const int idx = tid + it * NT;
        if (idx < IY * IC4) {
            const int r  = idx / IC4;
            const int c4 = idx - r * IC4;
            const int gr = r0 - 5 + r;
            const int gc = c0 - 8 + 4 * c4;
            const bool ok = ((unsigned)gr < (unsigned)H) &&
                            (xin || ((unsigned)gc < (unsigned)W));
            float4 lx = make_float4(0.f, 0.f, 0.f, 0.f), ly = lx;
            if (ok) {
                const size_t gi = ((size_t)gr << 9) + gc;
                lx = *reinterpret_cast<const float4*>(xp + gi);
                ly = *reinterpret_cast<const float4*>(yp + gi);
            }
            *reinterpret_cast<float4*>(&buf[r][8 * c4]) =
                make_float4(lx.x, ly.x, lx.y, ly.y);
            *reinterpret_cast<float4*>(&buf[r][8 * c4 + 4]) =
                make_float4(lx.z, ly.z, lx.w, ly.w);
        }
    }
    __syncthreads();

    // ---- Stage 2: horizontal conv, 8 consecutive cols per item ----
    // wave w<4: rows 16w..16w+15 (lane: row-low = l&7, row-mid = l>>5,
    //           cg = (l>>3)&3); wave 4 (lanes 0-39): rows 64-73, cg = l&3.
    {
        const int l   = tid & 63;
        const int wid = tid >> 6;
        int row, cg;
        if (wid < 4) {
            row = (wid << 4) + ((l >> 5) << 3) + (l & 7);
            cg  = (l >> 3) & 3;
        } else {
            row = 64 + (l >> 2);
            cg  = l & 3;
        }
        const int  cb  = cg << 3;                  // base output col 0,8,16,24
        const bool act = (wid < 4) || ((wid == 4) && (l < 40));
        if (act) {
            // taps kk=0..17: local col cb+3+kk -> word 2cb+6+2kk;
            // b128 reads cover words 2cb+4 .. 2cb+43 (q = (kk+1)>>1).
            const float* __restrict__ rb = &buf[row][2 * cb + 4];

            float2 A01[8], A23[8];
            float  A4[8];
#pragma unroll
            for (int j = 0; j < 8; ++j) {
                A01[j] = make_float2(0.f, 0.f);
                A23[j] = make_float2(0.f, 0.f);
                A4[j]  = 0.f;
            }

            float4 q4[10];
#pragma unroll
            for (int q = 0; q < 5; ++q)            // batch A
                q4[q] = *reinterpret_cast<const float4*>(rb + 4 * q);
#pragma unroll
            for (int kk = 0; kk < 8; ++kk) {
                const float4 f = q4[(kk + 1) >> 1];
                const float2 vv = (kk & 1) ? make_float2(f.x, f.y)
                                           : make_float2(f.z, f.w);
                const float2 pp  = pk_mul2(vv, vv);
                const float  pxy = vv.x * vv.y;
#pragma unroll
                for (int j = 0; j < 8; ++j) {
                    const int m = kk - j;
                    if (m >= 0 && m <= 10) {
                        const float2 w2 = make_float2(g[m], g[m]);
                        pk_fma2(A01[j], w2, vv);
                        pk_fma2(A23[j], w2, pp);
                        A4[j] = fmaf(g[m], pxy, A4[j]);
                    }
                }
            }
#pragma unroll
            for (int q = 5; q < 10; ++q)           // batch B
                q4[q] = *reinterpret_cast<const float4*>(rb + 4 * q);
#pragma unroll
            for (int kk = 8; kk < 18; ++kk) {
                const float4 f = q4[(kk + 1) >> 1];
                const float2 vv = (kk & 1) ? make_float2(f.x, f.y)
                                           : make_float2(f.z, f.w);
                const float2 pp  = pk_mul2(vv, vv);
                const float  pxy = vv.x * vv.y;
#pragma unroll
                for (int j = 0; j < 8; ++j) {
                    const int m = kk - j;
                    if (m >= 0 && m <= 10) {
                        const float2 w2 = make_float2(g[m], g[m]);
                        pk_fma2(A01[j], w2, vv);
                        pk_fma2(A23[j], w2, pp);
                        A4[j] = fmaf(g[m], pxy, A4[j]);
                    }
                }
            }
            // hf4 at words 4*(cb+j); hfx at words 128+cb (two b128)
#pragma unroll
            for (int j = 0; j < 8; ++j) {
                *reinterpret_cast<float4*>(&buf[row][4 * (cb + j)]) =
                    make_float4(A01[j].x, A01[j].y, A23[j].x, A23[j].y);
            }
            *reinterpret_cast<float4*>(&buf[row][128 + cb]) =
                make_float4(A4[0], A4[1], A4[2], A4[3]);
            *reinterpret_cast<float4*>(&buf[row][128 + cb + 4]) =
                make_float4(A4[4], A4[5], A4[6], A4[7]);
        }
    }
    __syncthreads();

    // ---- Stage 3: vertical conv + SSIM, 4 consecutive rows per thread ----
    {
        const int tx    = tid & 31;
        const int obase = (tid >> 5) << 2;       // first output row 0,4,..,60

        float2 acc01[4], acc23[4];
        float  acc4[4];
#pragma unroll
        for (int j = 0; j < 4; ++j) {
            acc01[j] = make_float2(0.f, 0.f);
            acc23[j] = make_float2(0.f, 0.f);
            acc4[j]  = 0.f;
        }
#pragma unroll
        for (int rr = 0; rr < 14; ++rr) {
            const float4 h4 =
                *reinterpret_cast<const float4*>(&buf[obase + rr][4 * tx]);
            const float  h5 = buf[obase + rr][128 + tx];
            const float2 h01 = make_float2(h4.x, h4.y);
            const float2 h23 = make_float2(h4.z, h4.w);
#pragma unroll
            for (int j = 0; j < 4; ++j) {
                const int m = rr - j;            // tap index for output j
                if (m >= 0 && m <= 10) {
                    const float2 w2 = make_float2(g[m], g[m]);
                    pk_fma2(acc01[j], w2, h01);
                    pk_fma2(acc23[j], w2, h23);
                    acc4[j] = fmaf(g[m], h5, acc4[j]);
                }
            }
        }

        float* __restrict__ op = out + (size_t)bc * H * W;
#pragma unroll
        for (int j = 0; j < 4; ++j) {
            const float2 a01  = acc01[j];
            const float2 musq = pk_mul2(a01, a01);     // (mu1^2, mu2^2)
            const float  mu12 = a01.x * a01.y;
            const float  s1   = acc23[j].x - musq.x;
            const float  s2   = acc23[j].y - musq.y;
            const float  s12  = acc4[j]    - mu12;
            const float num = fmaf(2.f, mu12, 1e-4f) * fmaf(2.f, s12, 9e-4f);
            const float den = ((musq.x + musq.y) + 1e-4f) * ((s1 + s2) + 9e-4f);
            op[(size_t)(r0 + obase + j) * W + c0 + tx] =
                num * __builtin_amdgcn_rcpf(den);
        }
    }
}

extern "C" void kernel_launch(void* const* d_in, const int* in_sizes, int n_in,
                              void* d_out, int out_size, void* d_ws, size_t ws_size,
                              hipStream_t stream) {
    const float* img_out    = (const float*)d_in[0];
    const float* img_target = (const float*)d_in[1];
    // d_in[2] is window_size==11; fixed by the problem, baked into the kernel.
    float* out = (float*)d_out;

    dim3 grid(W / TX, H / TY, BC);   // 16 x 8 x 48 = 6144 blocks
    ssim_kernel<<<grid, NT, 0, stream>>>(img_out, img_target, out);
}

// Round 10
// 57.678 us; speedup vs baseline: 1.6292x; 1.0062x over previous
//
#include <hip/hip_runtime.h>

// SSIM map — round-10: 8-row stage-3 items + paired-xy pk_fma.
// B=16, C=3, H=W=512, 11-tap separable gaussian (sigma=1.5).
//
// Base = round-9 (58.0us): 32x64 tile, 512 thr, union LDS [74][164]f
// (48.5KB -> 3 blk/CU), 2 barriers, pk math, 8-col stage-2 items,
// float4 stage-1, wave-local raw->hf aliasing, XCD-channel swizzle
// (FETCH 141->49MB; HBM now 17% of peak — memory is out of the picture).
//
// Round-9 residual: VALUBusy ~56%, occupancy ~56%, no pipe saturated.
// LDS issue audit: stage-3 = 14.3k of ~22k thread-level LDS ops/block
// (14 b128 + 14 b32 per thread, 3.5 reads/output). Changes:
//
// 1) Stage 3: 8 consecutive rows/thread (256 active threads, 32 cols x 8
//    row-groups): 18 reads/8 outputs = 2.25/output (-36% stage-3 LDS
//    wave-ops), halved per-output addressing. Same per-output tap order
//    (rr ascending, g[0..10]) -> bitwise-identical result.
// 2) xy channel paired across outputs (j,j+1): same pxy/h5 operand, weight
//    pair (g[m],g[m-1]) as SGPR pair, zero-padded at pair edges (exact
//    no-ops for these non-negative operands) -> ~4.9 scalar fma/tap becomes
//    ~2.67 pk_fma + 1 mov in BOTH conv stages (~-7% VALU).
//
// Watch: VGPR must stay <=84 (launch_bounds (512,6)); spills would show as
// WRITE_SIZE jump (round-8 signature) -> revert.

#define W     512
#define H     512
#define BC    48
#define TX    32
#define TY    64
#define IY    74          // TY + 10
#define IC4   12          // float4 cols staged per row (48 cols: c0-8..c0+39)
#define PITCH 164         // floats/row: 656B = 41 float4s (odd: bank stagger)
#define NT    512

__device__ __forceinline__ float2 pk_mul2(float2 a, float2 b) {
    float2 d;
    asm("v_pk_mul_f32 %0, %1, %2" : "=v"(d) : "v"(a), "v"(b));
    return d;
}
// acc = w*v + acc  (both lanes); w uniform -> SGPR pair
__device__ __forceinline__ void pk_fma2(float2& acc, float2 w, float2 v) {
    asm("v_pk_fma_f32 %0, %1, %2, %0" : "+v"(acc) : "s"(w), "v"(v));
}
// gaussian weight with zero padding outside [0,10] (compile-time folded)
__device__ __forceinline__ float gwf(const float* g, int m) {
    return (m >= 0 && m <= 10) ? g[m] : 0.f;
}

__global__ __launch_bounds__(NT, 6) void ssim_kernel(
    const float* __restrict__ x, const float* __restrict__ y,
    float* __restrict__ out)
{
    __shared__ __align__(16) float buf[IY][PITCH];   // 48544 B -> 3 blocks/CU

    // fp32-normalized gaussian, sigma=1.5, K=11 (matches np reference ~1e-7)
    const float g[11] = {
        0.00102838f, 0.00759875f, 0.03600077f, 0.10936069f, 0.21300553f,
        0.26601172f,
        0.21300553f, 0.10936069f, 0.03600077f, 0.00759875f, 0.00102838f};

    const int tid = threadIdx.x;

    // ---- XCD-channel swizzle: lin -> (xcd owns 768 consecutive tiles) ----
    const int lin  = blockIdx.x + (blockIdx.y << 4) + (blockIdx.z << 7);
    const int tile = ((lin & 7) * 768) + (lin >> 3);   // bijective, 6144=8*768
    const int bc   = tile >> 7;                        // channel 0..47
    const int tyi  = (tile >> 4) & 7;                  // tile row 0..7
    const int txi  = tile & 15;                        // tile col 0..15
    const int c0   = txi * TX;
    const int r0   = tyi * TY;

    const float* __restrict__ xp = x + (size_t)bc * H * W;
    const float* __restrict__ yp = y + (size_t)bc * H * W;

    const bool xin = (txi > 0) && (txi < (W / TX) - 1);

    // ---- Stage 1: global float4 -> LDS interleaved (x,y) pairs ----
    // item = r*12 + c4; cols gc = c0-8+4*c4 (aligned, never straddles edge)
#pragma unroll
    for (int it = 0; it < 2; ++it) {
        const int idx = tid + it * NT;
        if (idx < IY * IC4) {
            const int r  = idx / IC4;
            const int c4 = idx - r * IC4;
            const int gr = r0 - 5 + r;
            const int gc = c0 - 8 + 4 * c4;
            const bool ok = ((unsigned)gr < (unsigned)H) &&
                            (xin || ((unsigned)gc < (unsigned)W));
            float4 lx = make_float4(0.f, 0.f, 0.f, 0.f), ly = lx;
            if (ok) {
                const size_t gi = ((size_t)gr << 9) + gc;
                lx = *reinterpret_cast<const float4*>(xp + gi);
                ly = *reinterpret_cast<const float4*>(yp + gi);
            }
            *reinterpret_cast<float4*>(&buf[r][8 * c4]) =
                make_float4(lx.x, ly.x, lx.y, ly.y);
            *reinterpret_cast<float4*>(&buf[r][8 * c4 + 4]) =
                make_float4(lx.z, ly.z, lx.w, ly.w);
        }
    }
    __syncthreads();

    // ---- Stage 2: horizontal conv, 8 consecutive cols per item ----
    // wave w<4: rows 16w..16w+15 (lane: row-low = l&7, row-mid = l>>5,
    //           cg = (l>>3)&3); wave 4 (lanes 0-39): rows 64-73, cg = l&3.
    {
        const int l   = tid & 63;
        const int wid = tid >> 6;
        int row, cg;
        if (wid < 4) {
            row = (wid << 4) + ((l >> 5) << 3) + (l & 7);
            cg  = (l >> 3) & 3;
        } else {
            row = 64 + (l >> 2);
            cg  = l & 3;
        }
        const int  cb  = cg << 3;                  // base output col 0,8,16,24
        const bool act = (wid < 4) || ((wid == 4) && (l < 40));
        if (act) {
            // taps kk=0..17: local col cb+3+kk -> word 2cb+6+2kk;
            // b128 reads cover words 2cb+4 .. 2cb+43 (q = (kk+1)>>1).
            const float* __restrict__ rb = &buf[row][2 * cb + 4];

            float2 A01[8], A23[8], A4p[4];
#pragma unroll
            for (int j = 0; j < 8; ++j) {
                A01[j] = make_float2(0.f, 0.f);
                A23[j] = make_float2(0.f, 0.f);
            }
#pragma unroll
            for (int p = 0; p < 4; ++p) A4p[p] = make_float2(0.f, 0.f);

            float4 q4[10];
#pragma unroll
            for (int q = 0; q < 5; ++q)            // batch A
                q4[q] = *reinterpret_cast<const float4*>(rb + 4 * q);
#pragma unroll
            for (int kk = 0; kk < 8; ++kk) {
                const float4 f = q4[(kk + 1) >> 1];
                const float2 vv = (kk & 1) ? make_float2(f.x, f.y)
                                           : make_float2(f.z, f.w);
                const float2 pp   = pk_mul2(vv, vv);
                const float  pxy  = vv.x * vv.y;
                const float2 pxy2 = make_float2(pxy, pxy);
#pragma unroll
                for (int j = 0; j < 8; ++j) {
                    const int m = kk - j;
                    if (m >= 0 && m <= 10) {
                        const float2 w2 = make_float2(g[m], g[m]);
                        pk_fma2(A01[j], w2, vv);
                        pk_fma2(A23[j], w2, pp);
                    }
                }
#pragma unroll
                for (int p = 0; p < 4; ++p) {
                    const int m0 = kk - (p << 1);
                    if (m0 >= 0 && m0 <= 11) {
                        const float2 w2 = make_float2(gwf(g, m0), gwf(g, m0 - 1));
                        pk_fma2(A4p[p], w2, pxy2);
                    }
                }
            }
#pragma unroll
            for (int q = 5; q < 10; ++q)           // batch B
                q4[q] = *reinterpret_cast<const float4*>(rb + 4 * q);
#pragma unroll
            for (int kk = 8; kk < 18; ++kk) {
                const float4 f = q4[(kk + 1) >> 1];
                const float2 vv = (kk & 1) ? make_float2(f.x, f.y)
                                           : make_float2(f.z, f.w);
                const float2 pp   = pk_mul2(vv, vv);
                const float  pxy  = vv.x * vv.y;
                const float2 pxy2 = make_float2(pxy, pxy);
#pragma unroll
                for (int j = 0; j < 8; ++j) {
                    const int m = kk - j;
                    if (m >= 0 && m <= 10) {
                        const float2 w2 = make_float2(g[m], g[m]);
                        pk_fma2(A01[j], w2, vv);
                        pk_fma2(A23[j], w2, pp);
                    }
                }
#pragma unroll
                for (int p = 0; p < 4; ++p) {
                    const int m0 = kk - (p << 1);
                    if (m0 >= 0 && m0 <= 11) {
                        const float2 w2 = make_float2(gwf(g, m0), gwf(g, m0 - 1));
                        pk_fma2(A4p[p], w2, pxy2);
                    }
                }
            }
            // hf4 at words 4*(cb+j); hfx at words 128+cb (two b128)
#pragma unroll
            for (int j = 0; j < 8; ++j) {
                *reinterpret_cast<float4*>(&buf[row][4 * (cb + j)]) =
                    make_float4(A01[j].x, A01[j].y, A23[j].x, A23[j].y);
            }
            *reinterpret_cast<float4*>(&buf[row][128 + cb]) =
                make_float4(A4p[0].x, A4p[0].y, A4p[1].x, A4p[1].y);
            *reinterpret_cast<float4*>(&buf[row][128 + cb + 4]) =
                make_float4(A4p[2].x, A4p[2].y, A4p[3].x, A4p[3].y);
        }
    }
    __syncthreads();

    // ---- Stage 3: vertical conv + SSIM, 8 consecutive rows per thread ----
    // 256 active threads: tx = tid&31 (col), og = (tid>>5)*8 (rows og..og+7).
    // 18 hf row-reads amortized over 8 outputs (2.25 reads/output).
    if (tid < 256) {
        const int tx = tid & 31;
        const int og = (tid >> 5) << 3;          // first output row 0,8,..,56

        float2 acc01[8], acc23[8], acc4p[4];
#pragma unroll
        for (int j = 0; j < 8; ++j) {
            acc01[j] = make_float2(0.f, 0.f);
            acc23[j] = make_float2(0.f, 0.f);
        }
#pragma unroll
        for (int p = 0; p < 4; ++p) acc4p[p] = make_float2(0.f, 0.f);

#pragma unroll
        for (int rr = 0; rr < 18; ++rr) {
            const float4 h4 =
                *reinterpret_cast<const float4*>(&buf[og + rr][4 * tx]);
            const float  h5 = buf[og + rr][128 + tx];
            const float2 h01 = make_float2(h4.x, h4.y);
            const float2 h23 = make_float2(h4.z, h4.w);
            const float2 h55 = make_float2(h5, h5);
#pragma unroll
            for (int j = 0; j < 8; ++j) {
                const int m = rr - j;            // tap index for output j
                if (m >= 0 && m <= 10) {
                    const float2 w2 = make_float2(g[m], g[m]);
                    pk_fma2(acc01[j], w2, h01);
                    pk_fma2(acc23[j], w2, h23);
                }
            }
#pragma unroll
            for (int p = 0; p < 4; ++p) {
                const int m0 = rr - (p << 1);
                if (m0 >= 0 && m0 <= 11) {
                    const float2 w2 = make_float2(gwf(g, m0), gwf(g, m0 - 1));
                    pk_fma2(acc4p[p], w2, h55);
                }
            }
        }

        float* __restrict__ op = out + (size_t)bc * H * W;
#pragma unroll
        for (int j = 0; j < 8; ++j) {
            const float2 a01  = acc01[j];
            const float2 musq = pk_mul2(a01, a01);     // (mu1^2, mu2^2)
            const float  mu12 = a01.x * a01.y;
            const float  a4   = (j & 1) ? acc4p[j >> 1].y : acc4p[j >> 1].x;
            const float  s1   = acc23[j].x - musq.x;
            const float  s2   = acc23[j].y - musq.y;
            const float  s12  = a4 - mu12;
            const float num = fmaf(2.f, mu12, 1e-4f) * fmaf(2.f, s12, 9e-4f);
            const float den = ((musq.x + musq.y) + 1e-4f) * ((s1 + s2) + 9e-4f);
            op[(size_t)(r0 + og + j) * W + c0 + tx] =
                num * __builtin_amdgcn_rcpf(den);
        }
    }
}

extern "C" void kernel_launch(void* const* d_in, const int* in_sizes, int n_in,
                              void* d_out, int out_size, void* d_ws, size_t ws_size,
                              hipStream_t stream) {
    const float* img_out    = (const float*)d_in[0];
    const float* img_target = (const float*)d_in[1];
    // d_in[2] is window_size==11; fixed by the problem, baked into the kernel.
    float* out = (float*)d_out;

    dim3 grid(W / TX, H / TY, BC);   // 16 x 8 x 48 = 6144 blocks
    ssim_kernel<<<grid, NT, 0, stream>>>(img_out, img_target, out);
}